// Round 11
// baseline (391.418 us; speedup 1.0000x reference)
//
#include <hip/hip_runtime.h>
#include <hip/hip_bf16.h>
#include <math.h>

#define B_SZ    2
#define LSEQ    2048
#define DMODEL  1024
#define DINNER  2048
#define DSTATE  16
#define DCONV   4
#define DTRANK  64

#define NCHUNK  64
#define CLEN    (LSEQ / NCHUNK)   // 32

#define KSPLIT  8                 // GEMM3 split-K factor (K-chunk = 256)
#define NX      96                // DT_RANK + 2*DSTATE

typedef unsigned short u16;
typedef __bf16 bf16x8 __attribute__((ext_vector_type(8)));
typedef float  f32x4  __attribute__((ext_vector_type(4)));

static __device__ __forceinline__ float sigmoidf_(float x) {
    return 1.0f / (1.0f + __expf(-x));
}
static __device__ __forceinline__ u16 f2b(float f) {   // RNE f32 -> bf16
    unsigned int u = __float_as_uint(f);
    u = (u + 0x7fffu + ((u >> 16) & 1u)) >> 16;
    return (u16)u;
}
static __device__ __forceinline__ float b2f(u16 v) {
    return __uint_as_float(((unsigned int)v) << 16);
}

// Bijective XCD-chunked block swizzle (T1, m204): per-z-slice, requires
// (gridDim.x*gridDim.y) % 8 == 0.
static __device__ __forceinline__ void xcd_swizzle(int& bx, int& by) {
    const int gx  = gridDim.x;
    const int lin = by * gx + bx;
    const int cpx = (gx * gridDim.y) >> 3;
    const int wg  = (lin & 7) * cpx + (lin >> 3);
    bx = wg % gx;  by = wg / gx;
}

// ----------------------------------------------------------------------------
// prep_casts: all input casts in ONE dispatch (branch per block range).
//  [0,2048)      : x f32 -> xbf bf16 (straight, 8/thread)
//  [2048,6144)   : W_in  [1024][4096] -> WinT  [4096][1024]
//  [6144,6272)   : W_dt  [64][2048]   -> WdtT  [2048][64]
//  [6272,8320)   : W_out [2048][1024] -> WoutT [1024][2048]
// ----------------------------------------------------------------------------
static __device__ __forceinline__ void castT_body(
    const float* __restrict__ in, u16* __restrict__ out, int R, int C,
    int bx, int by, float t[32][33], int tid)
{
    const int r0 = by * 32, c0 = bx * 32;
    const int tr = tid >> 3;
    const int tc4 = (tid & 7) * 4;
    const float4 v = *reinterpret_cast<const float4*>(in + (size_t)(r0 + tr) * C + c0 + tc4);
    t[tr][tc4 + 0] = v.x; t[tr][tc4 + 1] = v.y; t[tr][tc4 + 2] = v.z; t[tr][tc4 + 3] = v.w;
    __syncthreads();
    union { u16 u[4]; uint2 q; } r;
    #pragma unroll
    for (int j = 0; j < 4; j++) r.u[j] = f2b(t[tc4 + j][tr]);
    *reinterpret_cast<uint2*>(out + (size_t)(c0 + tr) * R + r0 + tc4) = r.q;
}

__global__ __launch_bounds__(256) void prep_casts(
    const float* __restrict__ x,     u16* __restrict__ xbf,
    const float* __restrict__ W_in,  u16* __restrict__ WinT,
    const float* __restrict__ W_dt,  u16* __restrict__ WdtT,
    const float* __restrict__ W_out, u16* __restrict__ WoutT)
{
    __shared__ float t[32][33];
    const int b = blockIdx.x;
    const int tid = threadIdx.x;
    if (b < 2048) {
        const int i = b * 256 + tid;                 // over 4096*1024/8
        const float4* p = reinterpret_cast<const float4*>(x + (size_t)i * 8);
        float4 v0 = p[0], v1 = p[1];
        union { u16 u[8]; uint4 q; } r;
        r.u[0] = f2b(v0.x); r.u[1] = f2b(v0.y); r.u[2] = f2b(v0.z); r.u[3] = f2b(v0.w);
        r.u[4] = f2b(v1.x); r.u[5] = f2b(v1.y); r.u[6] = f2b(v1.z); r.u[7] = f2b(v1.w);
        reinterpret_cast<uint4*>(xbf)[i] = r.q;
    } else if (b < 6144) {
        const int lb = b - 2048;                     // grid (128, 32)
        castT_body(W_in, WinT, DMODEL, 2 * DINNER, lb % 128, lb / 128, t, tid);
    } else if (b < 6272) {
        const int lb = b - 6144;                     // grid (64, 2)
        castT_body(W_dt, WdtT, DTRANK, DINNER, lb % 64, lb / 64, t, tid);
    } else {
        const int lb = b - 6272;                     // grid (32, 64)
        castT_body(W_out, WoutT, DINNER, DMODEL, lb % 32, lb / 32, t, tid);
    }
}

// ----------------------------------------------------------------------------
// GEMM1: 256x256 tile, BK=64, 8 waves, double-buffered LDS, prefetch dist 2,
// counted vmcnt(8) (T3/T4), setprio (T5), XOR swizzle (T2), XCD swizzle (T1).
// ----------------------------------------------------------------------------
__global__ __launch_bounds__(512, 1) void gemm1_8ph(
    const u16* __restrict__ A, const u16* __restrict__ Bt,
    u16* __restrict__ xs_bf, u16* __restrict__ zs_bf)
{
    extern __shared__ u16 smem[];          // 128 KiB
    const int tid  = threadIdx.x;
    const int lane = tid & 63;
    const int wave = tid >> 6;
    const int wr = wave >> 2, wc = wave & 3;
    int bxs = blockIdx.x, bys = blockIdx.y;
    xcd_swizzle(bxs, bys);
    const int bm = bys * 256, bn = bxs * 256;
    const int lhi = lane >> 4, llo = lane & 15;
    constexpr int K  = DMODEL;
    constexpr int NT = K / 64;

    const int lrow8 = lane >> 3;
    const int gsrc  = ((lane & 7) ^ lrow8) * 8;

    f32x4 acc[8][4] = {};

    auto stage = [&](int kt, int buf) {
        #pragma unroll
        for (int h = 0; h < 2; ++h)
            #pragma unroll
            for (int i = 0; i < 2; ++i) {
                const int rowb = h * 128 + i * 64 + wave * 8;
                const int o16  = buf * 16384 + h * 8192 + i * 4096 + wave * 512;
                const u16* ga = A + (size_t)(bm + rowb + lrow8) * K + kt * 64 + gsrc;
                __builtin_amdgcn_global_load_lds(
                    (const __attribute__((address_space(1))) void*)ga,
                    (__attribute__((address_space(3))) void*)(smem + o16), 16, 0, 0);
                const u16* gb = Bt + (size_t)(bn + rowb + lrow8) * K + kt * 64 + gsrc;
                __builtin_amdgcn_global_load_lds(
                    (const __attribute__((address_space(1))) void*)gb,
                    (__attribute__((address_space(3))) void*)(smem + 32768 + o16), 16, 0, 0);
            }
    };
    auto lda = [&](int m, int ks, int buf) -> bf16x8 {
        const int row = wr * 128 + m * 16 + llo;
        const int g   = (ks * 4 + lhi) ^ (llo & 7);
        return *reinterpret_cast<const bf16x8*>(smem + buf * 16384 + row * 64 + g * 8);
    };
    auto ldb = [&](int n, int ks, int buf) -> bf16x8 {
        const int row = wc * 64 + n * 16 + llo;
        const int g   = (ks * 4 + lhi) ^ (llo & 7);
        return *reinterpret_cast<const bf16x8*>(smem + 32768 + buf * 16384 + row * 64 + g * 8);
    };

    stage(0, 0);
    stage(1, 1);
    asm volatile("s_waitcnt vmcnt(8)" ::: "memory");
    __builtin_amdgcn_s_barrier();

    #pragma unroll 2
    for (int t = 0; t < NT; ++t) {
        const int cur = t & 1;
        bf16x8 afr[4][2], bf0[2][2], bf1[2][2];

        #pragma unroll
        for (int m = 0; m < 4; ++m) { afr[m][0] = lda(m, 0, cur); afr[m][1] = lda(m, 1, cur); }
        #pragma unroll
        for (int n = 0; n < 2; ++n) { bf0[n][0] = ldb(n, 0, cur); bf0[n][1] = ldb(n, 1, cur); }
        __builtin_amdgcn_s_setprio(1);
        #pragma unroll
        for (int m = 0; m < 4; ++m)
            #pragma unroll
            for (int n = 0; n < 2; ++n) {
                acc[m][n] = __builtin_amdgcn_mfma_f32_16x16x32_bf16(afr[m][0], bf0[n][0], acc[m][n], 0, 0, 0);
                acc[m][n] = __builtin_amdgcn_mfma_f32_16x16x32_bf16(afr[m][1], bf0[n][1], acc[m][n], 0, 0, 0);
            }
        __builtin_amdgcn_s_setprio(0);

        #pragma unroll
        for (int n = 0; n < 2; ++n) { bf1[n][0] = ldb(2 + n, 0, cur); bf1[n][1] = ldb(2 + n, 1, cur); }
        __builtin_amdgcn_s_setprio(1);
        #pragma unroll
        for (int m = 0; m < 4; ++m)
            #pragma unroll
            for (int n = 0; n < 2; ++n) {
                acc[m][2 + n] = __builtin_amdgcn_mfma_f32_16x16x32_bf16(afr[m][0], bf1[n][0], acc[m][2 + n], 0, 0, 0);
                acc[m][2 + n] = __builtin_amdgcn_mfma_f32_16x16x32_bf16(afr[m][1], bf1[n][1], acc[m][2 + n], 0, 0, 0);
            }
        __builtin_amdgcn_s_setprio(0);

        #pragma unroll
        for (int m = 0; m < 4; ++m) { afr[m][0] = lda(4 + m, 0, cur); afr[m][1] = lda(4 + m, 1, cur); }
        __builtin_amdgcn_s_setprio(1);
        #pragma unroll
        for (int m = 0; m < 4; ++m)
            #pragma unroll
            for (int n = 0; n < 2; ++n) {
                acc[4 + m][2 + n] = __builtin_amdgcn_mfma_f32_16x16x32_bf16(afr[m][0], bf1[n][0], acc[4 + m][2 + n], 0, 0, 0);
                acc[4 + m][2 + n] = __builtin_amdgcn_mfma_f32_16x16x32_bf16(afr[m][1], bf1[n][1], acc[4 + m][2 + n], 0, 0, 0);
            }
        __builtin_amdgcn_s_setprio(0);

        __builtin_amdgcn_sched_barrier(0);
        __builtin_amdgcn_s_barrier();
        __builtin_amdgcn_sched_barrier(0);

        if (t + 2 < NT) stage(t + 2, cur);
        __builtin_amdgcn_s_setprio(1);
        #pragma unroll
        for (int m = 0; m < 4; ++m)
            #pragma unroll
            for (int n = 0; n < 2; ++n) {
                acc[4 + m][n] = __builtin_amdgcn_mfma_f32_16x16x32_bf16(afr[m][0], bf0[n][0], acc[4 + m][n], 0, 0, 0);
                acc[4 + m][n] = __builtin_amdgcn_mfma_f32_16x16x32_bf16(afr[m][1], bf0[n][1], acc[4 + m][n], 0, 0, 0);
            }
        __builtin_amdgcn_s_setprio(0);

        __builtin_amdgcn_sched_barrier(0);
        if (t + 2 < NT) { asm volatile("s_waitcnt vmcnt(8)" ::: "memory"); }
        else            { asm volatile("s_waitcnt vmcnt(0)" ::: "memory"); }
        __builtin_amdgcn_s_barrier();
        __builtin_amdgcn_sched_barrier(0);
    }

    const bool is_xs = (bn < DINNER);
    #pragma unroll
    for (int m = 0; m < 8; ++m) {
        const int row0 = bm + wr * 128 + m * 16 + lhi * 4;
        #pragma unroll
        for (int n = 0; n < 4; ++n) {
            const int col = bn + wc * 64 + n * 16 + llo;
            #pragma unroll
            for (int j = 0; j < 4; ++j) {
                float v = acc[m][n][j];
                if (is_xs) {
                    xs_bf[(size_t)(row0 + j) * DINNER + col] = f2b(v);
                } else {
                    v = v * sigmoidf_(v);
                    zs_bf[(size_t)(row0 + j) * DINNER + (col - DINNER)] = f2b(v);
                }
            }
        }
    }
}

// ----------------------------------------------------------------------------
// bf16 MFMA GEMM (m97 structure + T2 + T1), split-K capable via blockIdx.z.
//  EPI 2: o0 = bf16(softplus(acc + bias[col]))    [GEMM4]
//  EPI 3: unsafeAtomicAdd f32 into Cf             [GEMM6 split-K, out pre-zeroed]
// Klen = per-slice K; Kstride = full row stride.
// ----------------------------------------------------------------------------
template<int EPI>
__global__ __launch_bounds__(256) void gemm_mfma(
    const u16* __restrict__ A, const u16* __restrict__ Bt,
    float* __restrict__ Cf, u16* __restrict__ o0,
    const float* __restrict__ bias, int M, int N, int Klen, int Kstride, int ldc)
{
    __shared__ u16 As[128 * 32];
    __shared__ u16 Bs[128 * 32];
    const int tid  = threadIdx.x;
    const int lane = tid & 63;
    const int wave = tid >> 6;
    const int wr = wave >> 1, wc = wave & 1;
    int bxs = blockIdx.x, bys = blockIdx.y;
    xcd_swizzle(bxs, bys);
    const int bm = bys * 128, bn = bxs * 128;
    const int koff = blockIdx.z * Klen;
    const int lhi = lane >> 4;
    const int llo = lane & 15;

    f32x4 acc[4][4] = {};

    const int rs = (lhi ^ ((llo >> 1) & 3)) * 8;

    for (int k0 = 0; k0 < Klen; k0 += 32) {
        #pragma unroll
        for (int c = 0; c < 2; ++c) {
            const int s   = c * 256 + wave * 64 + lane;
            const int row = s >> 2, seg = s & 3;
            const int sseg = seg ^ ((row >> 1) & 3);
            const u16* ga = A  + (size_t)(bm + row) * Kstride + koff + k0 + sseg * 8;
            const u16* gb = Bt + (size_t)(bn + row) * Kstride + koff + k0 + sseg * 8;
            __builtin_amdgcn_global_load_lds(
                (const __attribute__((address_space(1))) void*)ga,
                (__attribute__((address_space(3))) void*)(As + (size_t)(c * 256 + wave * 64) * 8),
                16, 0, 0);
            __builtin_amdgcn_global_load_lds(
                (const __attribute__((address_space(1))) void*)gb,
                (__attribute__((address_space(3))) void*)(Bs + (size_t)(c * 256 + wave * 64) * 8),
                16, 0, 0);
        }
        __syncthreads();

        bf16x8 af[4], bfr[4];
        #pragma unroll
        for (int m = 0; m < 4; ++m)
            af[m] = *reinterpret_cast<const bf16x8*>(&As[(wr * 64 + m * 16 + llo) * 32 + rs]);
        #pragma unroll
        for (int n = 0; n < 4; ++n)
            bfr[n] = *reinterpret_cast<const bf16x8*>(&Bs[(wc * 64 + n * 16 + llo) * 32 + rs]);
        #pragma unroll
        for (int m = 0; m < 4; ++m)
            #pragma unroll
            for (int n = 0; n < 4; ++n)
                acc[m][n] = __builtin_amdgcn_mfma_f32_16x16x32_bf16(af[m], bfr[n], acc[m][n], 0, 0, 0);
        __syncthreads();
    }

    #pragma unroll
    for (int m = 0; m < 4; ++m) {
        const int row0 = bm + wr * 64 + m * 16 + lhi * 4;
        #pragma unroll
        for (int n = 0; n < 4; ++n) {
            const int col = bn + wc * 64 + n * 16 + llo;
            #pragma unroll
            for (int j = 0; j < 4; ++j) {
                float v = acc[m][n][j];
                if (EPI == 3) {
                    unsafeAtomicAdd(&Cf[(size_t)(row0 + j) * ldc + col], v);
                } else {
                    v += bias[col];
                    v = (v > 20.f) ? v : log1pf(__expf(v));   // softplus
                    o0[(size_t)(row0 + j) * ldc + col] = f2b(v);
                }
            }
        }
    }
}

// ----------------------------------------------------------------------------
// Causal depthwise conv (width 4, left pad 3) + bias + SiLU. bf16 in/out.
// ----------------------------------------------------------------------------
__global__ __launch_bounds__(256) void conv_silu_bf(
    const u16* __restrict__ xs, const float* __restrict__ conv_w,
    const float* __restrict__ conv_b, u16* __restrict__ u)
{
    const int g  = blockIdx.x * 256 + threadIdx.x;
    const int d8 = (g & 255) * 8;
    const int bl = g >> 8;
    const int l  = bl & (LSEQ - 1);

    float4 wv[8];
    #pragma unroll
    for (int j = 0; j < 8; j++)
        wv[j] = *reinterpret_cast<const float4*>(conv_w + (size_t)(d8 + j) * DCONV);

    float acc[8];
    #pragma unroll
    for (int j = 0; j < 8; j++) acc[j] = conv_b[d8 + j];

    #pragma unroll
    for (int k = 0; k < DCONV; k++) {
        const int l2 = l - (DCONV - 1) + k;
        if (l2 < 0) continue;
        const uint4 q = *reinterpret_cast<const uint4*>(
            xs + (size_t)(bl - (DCONV - 1) + k) * DINNER + d8);
        const u16* e = reinterpret_cast<const u16*>(&q);
        #pragma unroll
        for (int j = 0; j < 8; j++) {
            const float w = (k == 0) ? wv[j].x : (k == 1) ? wv[j].y : (k == 2) ? wv[j].z : wv[j].w;
            acc[j] = fmaf(b2f(e[j]), w, acc[j]);
        }
    }
    union { u16 u[8]; uint4 q; } r;
    #pragma unroll
    for (int j = 0; j < 8; j++) {
        const float v = acc[j];
        r.u[j] = f2b(v * sigmoidf_(v));
    }
    *reinterpret_cast<uint4*>(u + (size_t)bl * DINNER + d8) = r.q;
}

// ----------------------------------------------------------------------------
// GEMM3 split-K: partial[s][M][96] = u[M, ks] @ W_x[ks, :96], u is bf16.
// ----------------------------------------------------------------------------
__global__ __launch_bounds__(256) void gemm3_splitk(
    const u16* __restrict__ ubf, const float* __restrict__ Wx,
    float* __restrict__ partial)
{
    __shared__ float us[64][65];
    __shared__ float wsm[64][96];

    const int tid = threadIdx.x;
    const int r0 = blockIdx.x * 64;
    const int k0 = blockIdx.y * (DINNER / KSPLIT);

    const int orow = tid >> 2;
    const int oc0  = (tid & 3) * 24;

    float acc[24];
    #pragma unroll
    for (int j = 0; j < 24; j++) acc[j] = 0.f;

    for (int ks = 0; ks < DINNER / KSPLIT; ks += 64) {
        {
            const int row = tid >> 2;
            const int c16 = (tid & 3) << 4;
            const uint4* src = reinterpret_cast<const uint4*>(
                ubf + (size_t)(r0 + row) * DINNER + k0 + ks + c16);
            const uint4 q0 = src[0], q1 = src[1];
            const u16* e0 = reinterpret_cast<const u16*>(&q0);
            const u16* e1 = reinterpret_cast<const u16*>(&q1);
            #pragma unroll
            for (int j = 0; j < 8; j++) us[row][c16 + j]     = b2f(e0[j]);
            #pragma unroll
            for (int j = 0; j < 8; j++) us[row][c16 + 8 + j] = b2f(e1[j]);
        }
        #pragma unroll
        for (int j = 0; j < 6; j++) {
            const int fid = tid + j * 256;
            const int kr  = fid / 24;
            const int c4  = (fid % 24) * 4;
            *reinterpret_cast<float4*>(&wsm[kr][c4]) =
                *reinterpret_cast<const float4*>(Wx + (size_t)(k0 + ks + kr) * NX + c4);
        }
        __syncthreads();

        for (int kk = 0; kk < 64; ++kk) {
            const float uv = us[orow][kk];
            #pragma unroll
            for (int j = 0; j < 24; j++)
                acc[j] = fmaf(uv, wsm[kk][oc0 + j], acc[j]);
        }
        __syncthreads();
    }

    float* pp = partial + ((size_t)blockIdx.y * (B_SZ * LSEQ) + r0 + orow) * NX + oc0;
    #pragma unroll
    for (int j = 0; j < 24; j += 4)
        *reinterpret_cast<float4*>(pp + j) = make_float4(acc[j], acc[j+1], acc[j+2], acc[j+3]);
}

// reduce partials -> xdbl f32 [M][96]; also emit bf16 copy of cols 0..63 (GEMM4 A)
__global__ __launch_bounds__(256) void gemm3_reduce(
    const float* __restrict__ partial, float* __restrict__ xdbl,
    u16* __restrict__ x64bf)
{
    const int i = blockIdx.x * 256 + threadIdx.x;
    if (i >= B_SZ * LSEQ * NX / 4) return;
    float4 s = make_float4(0.f, 0.f, 0.f, 0.f);
    #pragma unroll
    for (int p = 0; p < KSPLIT; p++) {
        const float4 v = reinterpret_cast<const float4*>(
            partial + (size_t)p * (B_SZ * LSEQ) * NX)[i];
        s.x += v.x; s.y += v.y; s.z += v.z; s.w += v.w;
    }
    reinterpret_cast<float4*>(xdbl)[i] = s;

    const int col4 = (i % 24) * 4;
    if (col4 < DTRANK) {
        const int row = i / 24;
        union { u16 u[4]; uint2 q; } r;
        r.u[0] = f2b(s.x); r.u[1] = f2b(s.y); r.u[2] = f2b(s.z); r.u[3] = f2b(s.w);
        *reinterpret_cast<uint2*>(x64bf + (size_t)row * DTRANK + col4) = r.q;
    }
}

// ----------------------------------------------------------------------------
// Chunk-parallel selective scan (3 phases). delta comes in as bf16 (dl_bf).
// ----------------------------------------------------------------------------
__global__ __launch_bounds__(256) void scan_phase1(
    const u16* __restrict__ dl_bf, const u16* __restrict__ ubf,
    const float* __restrict__ xdbl, const float* __restrict__ A_log,
    float* __restrict__ hend, float* __restrict__ Sd)
{
    const int idx = blockIdx.x * 256 + threadIdx.x;
    const int d = idx & (DINNER - 1);
    const int c = (idx >> 11) & (NCHUNK - 1);
    const int b = idx >> 17;

    float a[DSTATE];
    #pragma unroll
    for (int n = 0; n < DSTATE; n++) a[n] = -__expf(A_log[d * DSTATE + n]);

    float h[DSTATE];
    #pragma unroll
    for (int n = 0; n < DSTATE; n++) h[n] = 0.f;
    float sd = 0.f;

    const int l0 = b * LSEQ + c * CLEN;
    for (int i = 0; i < CLEN; ++i) {
        const size_t r = (size_t)(l0 + i);
        const float dv = b2f(dl_bf[r * DINNER + d]);
        const float uv = b2f(ubf[r * DINNER + d]);
        sd += dv;
        float Bv[DSTATE];
        {
            const float4* bp = reinterpret_cast<const float4*>(xdbl + r * NX + DTRANK);
            float4 q;
            q = bp[0]; Bv[0]=q.x;  Bv[1]=q.y;  Bv[2]=q.z;  Bv[3]=q.w;
            q = bp[1]; Bv[4]=q.x;  Bv[5]=q.y;  Bv[6]=q.z;  Bv[7]=q.w;
            q = bp[2]; Bv[8]=q.x;  Bv[9]=q.y;  Bv[10]=q.z; Bv[11]=q.w;
            q = bp[3]; Bv[12]=q.x; Bv[13]=q.y; Bv[14]=q.z; Bv[15]=q.w;
        }
        const float du = dv * uv;
        #pragma unroll
        for (int n = 0; n < DSTATE; n++)
            h[n] = fmaf(__expf(dv * a[n]), h[n], du * Bv[n]);
    }

    float* hp = hend + ((size_t)(b * DINNER + d) * NCHUNK + c) * DSTATE;
    #pragma unroll
    for (int n = 0; n < DSTATE; n += 4)
        *reinterpret_cast<float4*>(hp + n) = make_float4(h[n], h[n+1], h[n+2], h[n+3]);
    Sd[(size_t)(b * DINNER + d) * NCHUNK + c] = sd;
}

// out-of-place carry combine: hin[c] = carry state entering chunk c.
// Separate in/out buffers -> alias-free -> loads pipeline across iterations.
__global__ __launch_bounds__(256) void scan_phase2(
    const float* __restrict__ hend, float* __restrict__ hin,
    const float* __restrict__ Sd, const float* __restrict__ A_log)
{
    const int idx = blockIdx.x * 256 + threadIdx.x;
    if (idx >= B_SZ * DINNER * DSTATE) return;
    const int n = idx & (DSTATE - 1);
    const int d = (idx >> 4) & (DINNER - 1);
    const int b = idx >> 15;

    const float an = -__expf(A_log[d * DSTATE + n]);
    const size_t base = (size_t)(b * DINNER + d) * NCHUNK;
    float carry = 0.f;
    #pragma unroll 4
    for (int c = 0; c < NCHUNK; ++c) {
        const float P = __expf(an * Sd[base + c]);
        const size_t off = (base + c) * DSTATE + n;
        hin[off] = carry;
        carry = fmaf(P, carry, hend[off]);
    }
}

__global__ __launch_bounds__(256) void scan_phase3(
    const u16* __restrict__ dl_bf, const u16* __restrict__ ubf,
    const u16* __restrict__ zs_bf, const float* __restrict__ xdbl,
    const float* __restrict__ A_log, const float* __restrict__ Dp,
    const float* __restrict__ hin, u16* __restrict__ ybf)
{
    const int idx = blockIdx.x * 256 + threadIdx.x;
    const int d = idx & (DINNER - 1);
    const int c = (idx >> 11) & (NCHUNK - 1);
    const int b = idx >> 17;

    float a[DSTATE];
    #pragma unroll
    for (int n = 0; n < DSTATE; n++) a[n] = -__expf(A_log[d * DSTATE + n]);
    const float Dd = Dp[d];

    float h[DSTATE];
    {
        const float* hp = hin + ((size_t)(b * DINNER + d) * NCHUNK + c) * DSTATE;
        #pragma unroll
        for (int n = 0; n < DSTATE; n += 4) {
            const float4 t = *reinterpret_cast<const float4*>(hp + n);
            h[n] = t.x; h[n+1] = t.y; h[n+2] = t.z; h[n+3] = t.w;
        }
    }

    const int l0 = b * LSEQ + c * CLEN;
    for (int i = 0; i < CLEN; ++i) {
        const size_t r = (size_t)(l0 + i);
        const float dv = b2f(dl_bf[r * DINNER + d]);
        const float uv = b2f(ubf[r * DINNER + d]);

        const float4* bp = reinterpret_cast<const float4*>(xdbl + r * NX + DTRANK);
        float Bv[DSTATE], Cv[DSTATE];
        {
            float4 t;
            t = bp[0]; Bv[0]=t.x;  Bv[1]=t.y;  Bv[2]=t.z;  Bv[3]=t.w;
            t = bp[1]; Bv[4]=t.x;  Bv[5]=t.y;  Bv[6]=t.z;  Bv[7]=t.w;
            t = bp[2]; Bv[8]=t.x;  Bv[9]=t.y;  Bv[10]=t.z; Bv[11]=t.w;
            t = bp[3]; Bv[12]=t.x; Bv[13]=t.y; Bv[14]=t.z; Bv[15]=t.w;
            t = bp[4]; Cv[0]=t.x;  Cv[1]=t.y;  Cv[2]=t.z;  Cv[3]=t.w;
            t = bp[5]; Cv[4]=t.x;  Cv[5]=t.y;  Cv[6]=t.z;  Cv[7]=t.w;
            t = bp[6]; Cv[8]=t.x;  Cv[9]=t.y;  Cv[10]=t.z; Cv[11]=t.w;
            t = bp[7]; Cv[12]=t.x; Cv[13]=t.y; Cv[14]=t.z; Cv[15]=t.w;
        }

        const float du = dv * uv;
        float yv = 0.f;
        #pragma unroll
        for (int n = 0; n < DSTATE; n++) {
            h[n] = fmaf(__expf(dv * a[n]), h[n], du * Bv[n]);
            yv = fmaf(h[n], Cv[n], yv);
        }
        yv = fmaf(uv, Dd, yv);

        const float g = b2f(zs_bf[r * DINNER + d]);
        ybf[r * DINNER + d] = f2b(yv * g);
    }
}

// ----------------------------------------------------------------------------
extern "C" void kernel_launch(void* const* d_in, const int* in_sizes, int n_in,
                              void* d_out, int out_size, void* d_ws, size_t ws_size,
                              hipStream_t stream) {
    const float* x      = (const float*)d_in[0];
    const float* W_in   = (const float*)d_in[1];
    const float* conv_w = (const float*)d_in[2];
    const float* conv_b = (const float*)d_in[3];
    const float* W_x    = (const float*)d_in[4];
    const float* W_dt   = (const float*)d_in[5];
    const float* b_dt   = (const float*)d_in[6];
    const float* A_log  = (const float*)d_in[7];
    const float* Dp     = (const float*)d_in[8];
    const float* W_out  = (const float*)d_in[9];
    float* out = (float*)d_out;

    const int M = B_SZ * LSEQ;   // 4096

    // workspace layout (~138 MB)
    float* ws     = (float*)d_ws;
    float* xdbl   = ws;                                           // [4096,96] f32
    float* hend   = xdbl + (size_t)M * NX;                        // [2,2048,64,16] f32
    float* hin    = hend + (size_t)B_SZ * DINNER * NCHUNK * DSTATE; // [2,2048,64,16] f32
    float* Sd     = hin  + (size_t)B_SZ * DINNER * NCHUNK * DSTATE;
    float* part   = Sd   + (size_t)B_SZ * DINNER * NCHUNK;        // [8,4096,96] f32
    u16*   xs_bf  = (u16*)(part + (size_t)KSPLIT * M * NX);       // [4096,2048] bf16
    u16*   zs_bf  = xs_bf + (size_t)M * DINNER;
    u16*   u_bf   = zs_bf + (size_t)M * DINNER;
    u16*   dl_bf  = u_bf  + (size_t)M * DINNER;
    u16*   xbf    = dl_bf + (size_t)M * DINNER;                   // [4096,1024] bf16
    u16*   WinT   = xbf   + (size_t)M * DMODEL;                   // [4096,1024] bf16
    u16*   WoutT  = WinT  + (size_t)M * DMODEL;                   // [1024,2048] bf16
    u16*   x64bf  = WoutT + (size_t)DMODEL * DINNER;              // [4096,64] bf16
    u16*   WdtT   = x64bf + (size_t)M * DTRANK;                   // [2048,64] bf16
    u16*   ybf    = xbf;                                          // aliases xbf+WinT

    dim3 blk(256);

    // 0) all input casts in one dispatch
    prep_casts<<<dim3(8320), blk, 0, stream>>>(
        x, xbf, W_in, WinT, W_dt, WdtT, W_out, WoutT);

    // zero-init out for GEMM6 split-K atomics (cheap, overlaps nothing critical)
    hipMemsetAsync(out, 0, (size_t)M * DMODEL * sizeof(float), stream);

    // 1) GEMM1 (256² pipelined + T1)
    gemm1_8ph<<<dim3((2 * DINNER) / 256, M / 256), dim3(512), 131072, stream>>>(
        xbf, WinT, xs_bf, zs_bf);

    // 2) u = silu(causal_conv(xs) + conv_b)
    conv_silu_bf<<<dim3((M * DINNER / 8) / 256), blk, 0, stream>>>(
        xs_bf, conv_w, conv_b, u_bf);

    // 3) xdbl = u @ W_x (split-K); reduce also emits x64bf (GEMM4 A, bf16)
    gemm3_splitk<<<dim3(M / 64, KSPLIT), blk, 0, stream>>>(u_bf, W_x, part);
    gemm3_reduce<<<dim3((M * NX / 4 + 255) / 256), blk, 0, stream>>>(part, xdbl, x64bf);

    // 4) GEMM4 (bf16 MFMA, K=64): dl_bf = bf16(softplus(x64 @ W_dt + b_dt))
    gemm_mfma<2><<<dim3(DINNER / 128, M / 128, 1), blk, 0, stream>>>(
        x64bf, WdtT, nullptr, dl_bf, b_dt, M, DINNER, DTRANK, DTRANK, DINNER);

    // 5) chunk-parallel scan
    scan_phase1<<<dim3((B_SZ * DINNER * NCHUNK) / 256), blk, 0, stream>>>(
        dl_bf, u_bf, xdbl, A_log, hend, Sd);
    scan_phase2<<<dim3((B_SZ * DINNER * DSTATE + 255) / 256), blk, 0, stream>>>(
        hend, hin, Sd, A_log);
    scan_phase3<<<dim3((B_SZ * DINNER * NCHUNK) / 256), blk, 0, stream>>>(
        dl_bf, u_bf, zs_bf, xdbl, A_log, Dp, hin, ybf);

    // 6) out += y @ W_out  (bf16 MFMA, split-K=2, atomic f32, T1)
    gemm_mfma<3><<<dim3(DMODEL / 128, M / 128, 2), blk, 0, stream>>>(
        ybf, WoutT, out, nullptr, nullptr, M, DMODEL, DINNER / 2, DINNER, DMODEL);
}